// Round 6
// baseline (319.875 us; speedup 1.0000x reference)
//
#include <hip/hip_runtime.h>
#include <stdint.h>

typedef __attribute__((ext_vector_type(8))) short short8;
typedef __attribute__((ext_vector_type(4))) float f32x4;
typedef unsigned short ushort_t;

#define SEQ   2048
#define BSZ   2
#define DIM   1024
#define NHEAD 16
#define HDIM  64
#define MROWS (BSZ*SEQ)   // 4096

__device__ __forceinline__ ushort_t f2bf(float f) {
  unsigned u = __float_as_uint(f);
  unsigned r = u + 0x7fffu + ((u >> 16) & 1u);
  return (ushort_t)(r >> 16);
}

__device__ __forceinline__ float fast_exp2(float x) {
#if __has_builtin(__builtin_amdgcn_exp2f)
  return __builtin_amdgcn_exp2f(x);
#else
  return exp2f(x);
#endif
}

// ---------------- amax: x + 4 weights in one dispatch ----------------
__device__ __forceinline__ void amax_reduce_store(float m, unsigned* slot) {
  __shared__ float wred[4];
  int wv = threadIdx.x >> 6, lane = threadIdx.x & 63;
#pragma unroll
  for (int off = 32; off > 0; off >>= 1) m = fmaxf(m, __shfl_down(m, off));
  if (lane == 0) wred[wv] = m;
  __syncthreads();
  if (threadIdx.x == 0) {
    float r = fmaxf(fmaxf(wred[0], wred[1]), fmaxf(wred[2], wred[3]));
    atomicMax(slot, __float_as_uint(r));
  }
}

__global__ __launch_bounds__(256) void amax5_kernel(
    const float* __restrict__ x, const float* w0, const float* w1,
    const float* w2, const float* w3, int n4x, int n4w,
    unsigned* __restrict__ slots) {
  int y = blockIdx.y;
  const float* p = (y == 0) ? x : (y == 1) ? w0 : (y == 2) ? w1 : (y == 3) ? w2 : w3;
  int n4 = (y == 0) ? n4x : n4w;
  const float4* x4 = (const float4*)p;
  float m = 0.f;
  for (int i = blockIdx.x * blockDim.x + threadIdx.x; i < n4; i += gridDim.x * blockDim.x) {
    float4 v = x4[i];
    m = fmaxf(m, fmaxf(fmaxf(fabsf(v.x), fabsf(v.y)), fmaxf(fabsf(v.z), fabsf(v.w))));
  }
  amax_reduce_store(m, slots + y);
}

// ------- quantize weights: integer codes round(w/s), stored exactly as bf16 -------
__global__ __launch_bounds__(256) void quant4_kernel(const float* w0, const float* w1,
                                                     const float* w2, const float* w3,
                                                     ushort_t* q0, ushort_t* q1,
                                                     ushort_t* q2, ushort_t* q3,
                                                     int n4, const unsigned* __restrict__ slots) {
  int y = blockIdx.y;
  const float* x = (y == 0) ? w0 : (y == 1) ? w1 : (y == 2) ? w2 : w3;
  ushort_t* qc = (y == 0) ? q0 : (y == 1) ? q1 : (y == 2) ? q2 : q3;
  float amax = __uint_as_float(slots[y + 1]);
  float s = fmaxf(amax / 127.0f, 1e-8f);
  float inv = 1.0f / s;
  const float4* x4 = (const float4*)x;
  ushort4* q4 = (ushort4*)qc;
  for (int i = blockIdx.x * blockDim.x + threadIdx.x; i < n4; i += gridDim.x * blockDim.x) {
    float4 v = x4[i];
    ushort4 o;
    o.x = f2bf(rintf(v.x * inv));
    o.y = f2bf(rintf(v.y * inv));
    o.z = f2bf(rintf(v.z * inv));
    o.w = f2bf(rintf(v.w * inv));
    q4[i] = o;
  }
}

// ------- fused: quantize activations (one read of x) + LoRA t = x @ A^T -------
template <int NL>
__global__ __launch_bounds__(256) void lora_quant_kernel(
    const float* __restrict__ x, const unsigned* __restrict__ slot,
    ushort_t* __restrict__ xc,
    const float* __restrict__ A0, const float* __restrict__ A1, const float* __restrict__ A2,
    float* __restrict__ t0, float* __restrict__ t1, float* __restrict__ t2) {
  const int row = blockIdx.x;
  const int tid = threadIdx.x;
  const int k0 = tid * 4;
  float amax = __uint_as_float(*slot);
  float s = fmaxf(amax / 127.0f, 1e-8f);
  float inv = 1.0f / s;

  float4 xv = *(const float4*)&x[(size_t)row * DIM + k0];
  ushort4 qo;
  qo.x = f2bf(rintf(xv.x * inv));
  qo.y = f2bf(rintf(xv.y * inv));
  qo.z = f2bf(rintf(xv.z * inv));
  qo.w = f2bf(rintf(xv.w * inv));
  *(ushort4*)&xc[(size_t)row * DIM + k0] = qo;

  float p[NL * 8];
#pragma unroll
  for (int r = 0; r < 8; r++) {
    float4 a = *(const float4*)&A0[r * DIM + k0];
    p[r] = xv.x * a.x + xv.y * a.y + xv.z * a.z + xv.w * a.w;
    if (NL > 1) {
      float4 a1 = *(const float4*)&A1[r * DIM + k0];
      p[8 + r] = xv.x * a1.x + xv.y * a1.y + xv.z * a1.z + xv.w * a1.w;
    }
    if (NL > 2) {
      float4 a2 = *(const float4*)&A2[r * DIM + k0];
      p[16 + r] = xv.x * a2.x + xv.y * a2.y + xv.z * a2.z + xv.w * a2.w;
    }
  }
#pragma unroll
  for (int j = 0; j < NL * 8; j++) {
    float v = p[j];
#pragma unroll
    for (int off = 32; off > 0; off >>= 1) v += __shfl_down(v, off);
    p[j] = v;
  }
  __shared__ float red[4][24];
  int wv = tid >> 6, lane = tid & 63;
  if (lane == 0) {
#pragma unroll
    for (int j = 0; j < NL * 8; j++) red[wv][j] = p[j];
  }
  __syncthreads();
  if (tid < NL * 8) {
    int j = tid;
    float sv = red[0][j] + red[1][j] + red[2][j] + red[3][j];
    float* tp = (j < 8) ? t0 : ((j < 16) ? t1 : t2);
    tp[(size_t)row * 8 + (j & 7)] = sv;
  }
}

// ---------------- projection GEMM on integer codes (exact) ----------------
template <bool BF16OUT, int BN>
__device__ __forceinline__ void proj_body(
    const ushort_t* __restrict__ Ac, const ushort_t* __restrict__ Wc,
    const unsigned* __restrict__ sxslot, const unsigned* __restrict__ swslot,
    const float* __restrict__ bias, const float* __restrict__ t,
    const float* __restrict__ Bl, void* __restrict__ Cout,
    int m0, int n0) {
  __shared__ alignas(16) ushort_t As[128 * 64];
  __shared__ alignas(16) ushort_t Bs[BN * 64];
  __shared__ float Ts[128 * 8];
  __shared__ float Bls[BN * 8];
  __shared__ float biass[BN];

  const int tid = threadIdx.x;
  constexpr int NJ = BN / 32;
  constexpr int BITS = BN * 8 / 256;

  for (int i = tid; i < 128 * 8; i += 256) Ts[i] = t[(size_t)m0 * 8 + i];
  for (int i = tid; i < BN * 8; i += 256) Bls[i] = Bl[(size_t)n0 * 8 + i];
  if (tid < BN) biass[tid] = bias[n0 + tid];

  f32x4 acc[4][NJ];
#pragma unroll
  for (int i = 0; i < 4; i++)
#pragma unroll
    for (int j = 0; j < NJ; j++) {
      acc[i][j][0] = 0.f; acc[i][j][1] = 0.f; acc[i][j][2] = 0.f; acc[i][j][3] = 0.f;
    }

  const int wv = tid >> 6, lane = tid & 63;
  const int wr = wv >> 1, wc = wv & 1;
  const int l15 = lane & 15, hi = lane >> 4;

  for (int kt = 0; kt < 16; kt++) {
    const int k0 = kt * 64;
#pragma unroll
    for (int it = 0; it < 4; it++) {
      int idx = it * 256 + tid;
      int r = idx >> 3, c = idx & 7;
      *(int4*)&As[r * 64 + (c ^ (r & 7)) * 8] = *(const int4*)&Ac[(size_t)(m0 + r) * DIM + k0 + c * 8];
    }
#pragma unroll
    for (int it = 0; it < BITS; it++) {
      int idx = it * 256 + tid;
      int r = idx >> 3, c = idx & 7;
      *(int4*)&Bs[r * 64 + (c ^ (r & 7)) * 8] = *(const int4*)&Wc[(size_t)(n0 + r) * DIM + k0 + c * 8];
    }
    __syncthreads();
#pragma unroll
    for (int ks = 0; ks < 2; ks++) {
      short8 a[4], b[NJ];
#pragma unroll
      for (int i = 0; i < 4; i++) {
        int row = wr * 64 + i * 16 + l15;
        a[i] = *(const short8*)&As[row * 64 + ((ks * 4 + hi) ^ (row & 7)) * 8];
      }
#pragma unroll
      for (int j = 0; j < NJ; j++) {
        int col = wc * (BN / 2) + j * 16 + l15;
        b[j] = *(const short8*)&Bs[col * 64 + ((ks * 4 + hi) ^ (col & 7)) * 8];
      }
      __builtin_amdgcn_s_setprio(1);
#pragma unroll
      for (int i = 0; i < 4; i++)
#pragma unroll
        for (int j = 0; j < NJ; j++)
          acc[i][j] = __builtin_amdgcn_mfma_f32_16x16x32_bf16(a[i], b[j], acc[i][j], 0, 0, 0);
      __builtin_amdgcn_s_setprio(0);
    }
    __syncthreads();
  }

  float sx = fmaxf(__uint_as_float(*sxslot) / 127.0f, 1e-8f);
  float sw = fmaxf(__uint_as_float(*swslot) / 127.0f, 1e-8f);
  float ss = sx * sw;
#pragma unroll
  for (int i = 0; i < 4; i++) {
#pragma unroll
    for (int rr = 0; rr < 4; rr++) {
      int rl = wr * 64 + i * 16 + hi * 4 + rr;
      float tv[8];
#pragma unroll
      for (int q = 0; q < 8; q++) tv[q] = Ts[rl * 8 + q];
#pragma unroll
      for (int j = 0; j < NJ; j++) {
        int cl = wc * (BN / 2) + j * 16 + l15;
        float lr = 0.f;
#pragma unroll
        for (int q = 0; q < 8; q++) lr += tv[q] * Bls[cl * 8 + q];
        float val = acc[i][j][rr] * ss + biass[cl] + 2.0f * lr;
        if (BF16OUT)
          ((ushort_t*)Cout)[(size_t)(m0 + rl) * DIM + n0 + cl] = f2bf(val);
        else
          ((float*)Cout)[(size_t)(m0 + rl) * DIM + n0 + cl] = val;
      }
    }
  }
}

struct ProjSet {
  const ushort_t* W; const unsigned* sw; const float* bias;
  const float* t; const float* Bl; ushort_t* out;
};

__global__ __launch_bounds__(256) void proj_qkv_kernel(
    const ushort_t* __restrict__ Ac, const unsigned* __restrict__ sxslot,
    ProjSet pq, ProjSet pk, ProjSet pv) {
  ProjSet P = (blockIdx.z == 0) ? pq : (blockIdx.z == 1) ? pk : pv;
  proj_body<true, 128>(Ac, P.W, sxslot, P.sw, P.bias, P.t, P.Bl, P.out,
                       blockIdx.y * 128, blockIdx.x * 128);
}

__global__ __launch_bounds__(256) void proj_out_kernel(
    const ushort_t* __restrict__ Ac, const ushort_t* __restrict__ Wc,
    const unsigned* __restrict__ sxslot, const unsigned* __restrict__ swslot,
    const float* __restrict__ bias, const float* __restrict__ t,
    const float* __restrict__ Bl, float* __restrict__ Cout) {
  proj_body<false, 64>(Ac, Wc, sxslot, swslot, bias, t, Bl, Cout,
                       blockIdx.y * 128, blockIdx.x * 64);
}

// ---- V transpose, 256-thread LDS-tiled: vb[token][1024] bf16 -> vT[bh*64+d][2048] ----
__global__ __launch_bounds__(256) void vtrans_kernel(const ushort_t* __restrict__ vb,
                                                     ushort_t* __restrict__ vT) {
  __shared__ alignas(16) ushort_t Lt[64 * 72];
  const int s0 = blockIdx.x * 64;
  const int bh = blockIdx.y;
  const int b = bh >> 4, h = bh & 15;
  const int tid = threadIdx.x;
#pragma unroll
  for (int it = 0; it < 2; it++) {
    int g = it * 256 + tid;
    int r = g >> 3, c = g & 7;
    *(int4*)&Lt[r * 72 + c * 8] =
        *(const int4*)&vb[(size_t)(b * SEQ + s0 + r) * DIM + h * 64 + c * 8];
  }
  __syncthreads();
#pragma unroll
  for (int it = 0; it < 2; it++) {
    int g = it * 256 + tid;
    int d = g >> 3, c = g & 7;
    union { int4 v; ushort_t u[8]; } out;
#pragma unroll
    for (int j = 0; j < 8; j++) out.u[j] = Lt[(c * 8 + j) * 72 + d];
    *(int4*)&vT[((size_t)bh * 64 + d) * SEQ + s0 + c * 8] = out.v;
  }
}

// ---------------- flash attention v5: split-K=2, partial outputs ----------------
__global__ __launch_bounds__(256) void attn5_kernel(
    const ushort_t* __restrict__ qb, const ushort_t* __restrict__ kb,
    const ushort_t* __restrict__ vT, const float* __restrict__ mask,
    float* __restrict__ pO0, float* __restrict__ pO1,
    float2* __restrict__ pml) {
  __shared__ alignas(16) ushort_t Ks[64 * 64];
  __shared__ alignas(16) ushort_t Vs[64 * 64];   // Vs[d][key]
  __shared__ alignas(16) ushort_t Ps[128 * 72];
  __shared__ float maskv[64];

  const float LOG2E = 1.44269504088896f;
  const float SCL2 = 0.125f * LOG2E;
  const float THR2 = 8.0f * LOG2E;

  // 1024 blocks; 128 consecutive logicals per XCD. sp = K-split half.
  const int lin = blockIdx.x;
  const int logical = (lin & 7) * 128 + (lin >> 3);
  const int sp = logical >> 9;            // 0 or 1
  const int rem = logical & 511;
  const int bh = rem >> 4;                // 0..31
  const int qt = rem & 15;                // 0..15
  const int b = bh >> 4, h = bh & 15;
  const size_t tokbase = (size_t)b * SEQ;
  const int q0 = qt * 128;
  float* __restrict__ pO = sp ? pO1 : pO0;

  const int tid = threadIdx.x;
  const int wv = tid >> 6, lane = tid & 63, l15 = lane & 15, hi = lane >> 4;

  short8 qf[2][2];
#pragma unroll
  for (int rb = 0; rb < 2; rb++)
#pragma unroll
    for (int ks = 0; ks < 2; ks++) {
      int row = q0 + wv * 32 + rb * 16 + l15;
      qf[rb][ks] = *(const short8*)&qb[(tokbase + row) * DIM + h * 64 + ks * 32 + hi * 8];
    }

  float mo[2][4], ls[2][4];
  f32x4 o[2][4];
#pragma unroll
  for (int rb = 0; rb < 2; rb++)
#pragma unroll
    for (int r = 0; r < 4; r++) { mo[rb][r] = -1e30f; ls[rb][r] = 0.f; }
#pragma unroll
  for (int rb = 0; rb < 2; rb++)
#pragma unroll
    for (int d = 0; d < 4; d++) { o[rb][d][0] = 0.f; o[rb][d][1] = 0.f; o[rb][d][2] = 0.f; o[rb][d][3] = 0.f; }

  for (int kt = sp * 16; kt < sp * 16 + 16; kt++) {
    const int k0 = kt * 64;
    __syncthreads();
    if (tid < 64) maskv[tid] = (1.0f - mask[tokbase + k0 + tid]) * (-10000.0f * LOG2E);
#pragma unroll
    for (int it = 0; it < 2; it++) {
      int g = it * 256 + tid;
      int r = g >> 3, c = g & 7;
      int slot = (c ^ (r & 7)) * 8;
      *(int4*)&Ks[r * 64 + slot] = *(const int4*)&kb[(tokbase + k0 + r) * DIM + h * 64 + c * 8];
      *(int4*)&Vs[r * 64 + slot] = *(const int4*)&vT[((size_t)bh * 64 + r) * SEQ + k0 + c * 8];
    }
    __syncthreads();

    // S = Q K^T (base-2 domain)
    f32x4 s[2][4];
#pragma unroll
    for (int rb = 0; rb < 2; rb++)
#pragma unroll
      for (int cb = 0; cb < 4; cb++) { s[rb][cb][0] = 0.f; s[rb][cb][1] = 0.f; s[rb][cb][2] = 0.f; s[rb][cb][3] = 0.f; }
#pragma unroll
    for (int ks = 0; ks < 2; ks++) {
      short8 kf[4];
#pragma unroll
      for (int cb = 0; cb < 4; cb++) {
        int row = cb * 16 + l15;
        kf[cb] = *(const short8*)&Ks[row * 64 + (((ks * 4 + hi) ^ (row & 7))) * 8];
      }
      __builtin_amdgcn_s_setprio(1);
#pragma unroll
      for (int rb = 0; rb < 2; rb++)
#pragma unroll
        for (int cb = 0; cb < 4; cb++)
          s[rb][cb] = __builtin_amdgcn_mfma_f32_16x16x32_bf16(qf[rb][ks], kf[cb], s[rb][cb], 0, 0, 0);
      __builtin_amdgcn_s_setprio(0);
    }
#pragma unroll
    for (int rb = 0; rb < 2; rb++)
#pragma unroll
      for (int cb = 0; cb < 4; cb++) {
        float mk = maskv[cb * 16 + l15];
#pragma unroll
        for (int r = 0; r < 4; r++) s[rb][cb][r] = s[rb][cb][r] * SCL2 + mk;
      }

    // online softmax, base-2, defer-max (T13)
    float tmv[2][4];
    bool need = false;
#pragma unroll
    for (int rb = 0; rb < 2; rb++)
#pragma unroll
      for (int r = 0; r < 4; r++) {
        float tm = fmaxf(fmaxf(s[rb][0][r], s[rb][1][r]), fmaxf(s[rb][2][r], s[rb][3][r]));
#pragma unroll
        for (int mm = 1; mm < 16; mm <<= 1) tm = fmaxf(tm, __shfl_xor(tm, mm));
        tmv[rb][r] = tm;
        need = need || (tm > mo[rb][r] + THR2);
      }
    if (__any(need)) {
#pragma unroll
      for (int rb = 0; rb < 2; rb++)
#pragma unroll
        for (int r = 0; r < 4; r++) {
          float mn = fmaxf(mo[rb][r], tmv[rb][r]);
          float al = fast_exp2(mo[rb][r] - mn);
          mo[rb][r] = mn;
          ls[rb][r] *= al;
#pragma unroll
          for (int d = 0; d < 4; d++) o[rb][d][r] *= al;
        }
    }
    float rs[2][4];
#pragma unroll
    for (int rb = 0; rb < 2; rb++)
#pragma unroll
      for (int r = 0; r < 4; r++) rs[rb][r] = 0.f;
#pragma unroll
    for (int rb = 0; rb < 2; rb++)
#pragma unroll
      for (int cb = 0; cb < 4; cb++)
#pragma unroll
        for (int r = 0; r < 4; r++) {
          float pv = fast_exp2(s[rb][cb][r] - mo[rb][r]);
          s[rb][cb][r] = pv;
          rs[rb][r] += pv;
        }
#pragma unroll
    for (int rb = 0; rb < 2; rb++)
#pragma unroll
      for (int r = 0; r < 4; r++) {
        float v = rs[rb][r];
#pragma unroll
        for (int mm = 1; mm < 16; mm <<= 1) v += __shfl_xor(v, mm);
        ls[rb][r] += v;
      }
    // P -> LDS (wave-private rows)
#pragma unroll
    for (int rb = 0; rb < 2; rb++)
#pragma unroll
      for (int cb = 0; cb < 4; cb++)
#pragma unroll
        for (int r = 0; r < 4; r++)
          Ps[(wv * 32 + rb * 16 + hi * 4 + r) * 72 + cb * 16 + l15] = f2bf(s[rb][cb][r]);
    // O += P V
#pragma unroll
    for (int ks = 0; ks < 2; ks++) {
      short8 pf[2];
#pragma unroll
      for (int rb = 0; rb < 2; rb++) {
        int row = wv * 32 + rb * 16 + l15;
        pf[rb] = *(const short8*)&Ps[row * 72 + ks * 32 + hi * 8];
      }
      short8 vf[4];
#pragma unroll
      for (int db = 0; db < 4; db++) {
        int row = db * 16 + l15;
        vf[db] = *(const short8*)&Vs[row * 64 + (((ks * 4 + hi) ^ (row & 7))) * 8];
      }
      __builtin_amdgcn_s_setprio(1);
#pragma unroll
      for (int rb = 0; rb < 2; rb++)
#pragma unroll
        for (int db = 0; db < 4; db++)
          o[rb][db] = __builtin_amdgcn_mfma_f32_16x16x32_bf16(pf[rb], vf[db], o[rb][db], 0, 0, 0);
      __builtin_amdgcn_s_setprio(0);
    }
  }

  // epilogue: write unnormalized partial O (f32) + per-row (m, l)
#pragma unroll
  for (int rb = 0; rb < 2; rb++)
#pragma unroll
    for (int r = 0; r < 4; r++) {
      int qrow = q0 + wv * 32 + rb * 16 + hi * 4 + r;
      size_t row = tokbase + qrow;
#pragma unroll
      for (int db = 0; db < 4; db++)
        pO[row * DIM + h * 64 + db * 16 + l15] = o[rb][db][r];
      if (l15 == 0)
        pml[sp * (32 * SEQ) + (bh << 11) + qrow] = make_float2(mo[rb][r], ls[rb][r]);
    }
}

// ---------------- merge split-K partials + fused amax ----------------
__global__ __launch_bounds__(256) void attn_merge_kernel(
    const float* __restrict__ pO0, const float* __restrict__ pO1,
    const float2* __restrict__ pml, float* __restrict__ abuf,
    unsigned* __restrict__ amax_slot) {
  const int row = blockIdx.x;          // 0..4095
  const int tid = threadIdx.x;
  const int col = tid * 4;
  const int b = row >> 11, sr = row & 2047;
  const int h = col >> 6;
  const int bh = b * 16 + h;

  float2 ml0 = pml[(bh << 11) + sr];
  float2 ml1 = pml[(32 * SEQ) + (bh << 11) + sr];
  float m = fmaxf(ml0.x, ml1.x);
  float a0 = fast_exp2(ml0.x - m);
  float a1 = fast_exp2(ml1.x - m);
  float invl = 1.0f / (ml0.y * a0 + ml1.y * a1);

  size_t off = (size_t)row * DIM + col;
  float4 o0 = *(const float4*)&pO0[off];
  float4 o1 = *(const float4*)&pO1[off];
  float4 res;
  res.x = (o0.x * a0 + o1.x * a1) * invl;
  res.y = (o0.y * a0 + o1.y * a1) * invl;
  res.z = (o0.z * a0 + o1.z * a1) * invl;
  res.w = (o0.w * a0 + o1.w * a1) * invl;
  *(float4*)&abuf[off] = res;

  float am = fmaxf(fmaxf(fabsf(res.x), fabsf(res.y)), fmaxf(fabsf(res.z), fabsf(res.w)));
  amax_reduce_store(am, amax_slot);
}

// ---------------- launcher ----------------
extern "C" void kernel_launch(void* const* d_in, const int* in_sizes, int n_in,
                              void* d_out, int out_size, void* d_ws, size_t ws_size,
                              hipStream_t stream) {
  const float* x     = (const float*)d_in[0];
  const float* mask  = (const float*)d_in[1];
  const float* q_W   = (const float*)d_in[2];
  const float* q_b   = (const float*)d_in[3];
  const float* q_A   = (const float*)d_in[4];
  const float* q_B   = (const float*)d_in[5];
  const float* k_W   = (const float*)d_in[6];
  const float* k_b   = (const float*)d_in[7];
  const float* k_A   = (const float*)d_in[8];
  const float* k_B   = (const float*)d_in[9];
  const float* v_W   = (const float*)d_in[10];
  const float* v_b   = (const float*)d_in[11];
  const float* v_A   = (const float*)d_in[12];
  const float* v_B   = (const float*)d_in[13];
  const float* o_W   = (const float*)d_in[14];
  const float* o_b   = (const float*)d_in[15];
  const float* o_A   = (const float*)d_in[16];
  const float* o_B   = (const float*)d_in[17];
  float* out = (float*)d_out;

  char* ws = (char*)d_ws;
  const size_t MB = 1u << 20;
  unsigned* slots = (unsigned*)ws;                  // 6 amax slots
  float* t_q = (float*)(ws + 4096);
  float* t_k = t_q + MROWS * 8;
  float* t_v = t_k + MROWS * 8;
  float* t_o = t_v + MROWS * 8;
  ushort_t* xc  = (ushort_t*)(ws + 1 * MB);
  ushort_t* qWc = (ushort_t*)(ws + 9 * MB);
  ushort_t* kWc = (ushort_t*)(ws + 11 * MB);
  ushort_t* vWc = (ushort_t*)(ws + 13 * MB);
  ushort_t* oWc = (ushort_t*)(ws + 15 * MB);
  ushort_t* qbb = (ushort_t*)(ws + 17 * MB);
  ushort_t* kbb = (ushort_t*)(ws + 25 * MB);
  ushort_t* vbb = (ushort_t*)(ws + 33 * MB);
  ushort_t* vTb = (ushort_t*)(ws + 41 * MB);
  float*    abuf = (float*)(ws + 49 * MB);          // also pO0 (merged in place)
  ushort_t* ac  = (ushort_t*)(ws + 65 * MB);
  float*    pO1 = (float*)(ws + 73 * MB);           // 16 MB
  float2*   pml = (float2*)(ws + 89 * MB);          // 2*32*2048*8B = 1 MB

  (void)hipMemsetAsync(ws, 0, 64, stream);

  const int NX4 = (MROWS * DIM) / 4;
  const int NW4 = (DIM * DIM) / 4;

  amax5_kernel<<<dim3(256, 5), 256, 0, stream>>>(x, q_W, k_W, v_W, o_W, NX4, NW4, slots);
  quant4_kernel<<<dim3(128, 4), 256, 0, stream>>>(q_W, k_W, v_W, o_W,
                                                  qWc, kWc, vWc, oWc, NW4, slots);

  lora_quant_kernel<3><<<MROWS, 256, 0, stream>>>(x, slots + 0, xc, q_A, k_A, v_A,
                                                  t_q, t_k, t_v);

  ProjSet pq = { qWc, slots + 1, q_b, t_q, q_B, qbb };
  ProjSet pk = { kWc, slots + 2, k_b, t_k, k_B, kbb };
  ProjSet pv = { vWc, slots + 3, v_b, t_v, v_B, vbb };
  proj_qkv_kernel<<<dim3(DIM / 128, MROWS / 128, 3), 256, 0, stream>>>(xc, slots + 0, pq, pk, pv);

  vtrans_kernel<<<dim3(SEQ / 64, BSZ * NHEAD), 256, 0, stream>>>(vbb, vTb);

  attn5_kernel<<<1024, 256, 0, stream>>>(qbb, kbb, vTb, mask, abuf, pO1, pml);
  attn_merge_kernel<<<MROWS, 256, 0, stream>>>(abuf, pO1, pml, abuf, slots + 5);

  lora_quant_kernel<1><<<MROWS, 256, 0, stream>>>(abuf, slots + 5, ac, o_A, nullptr, nullptr,
                                                  t_o, nullptr, nullptr);

  proj_out_kernel<<<dim3(DIM / 64, MROWS / 128), 256, 0, stream>>>(
      ac, oWc, slots + 5, slots + 4, o_b, t_o, o_B, out);
}

// Round 7
// 267.726 us; speedup vs baseline: 1.1948x; 1.1948x over previous
//
#include <hip/hip_runtime.h>
#include <stdint.h>

typedef __attribute__((ext_vector_type(8))) short short8;
typedef __attribute__((ext_vector_type(4))) float f32x4;
typedef unsigned short ushort_t;

#define SEQ   2048
#define BSZ   2
#define DIM   1024
#define NHEAD 16
#define HDIM  64
#define MROWS (BSZ*SEQ)   // 4096

__device__ __forceinline__ ushort_t f2bf(float f) {
  unsigned u = __float_as_uint(f);
  unsigned r = u + 0x7fffu + ((u >> 16) & 1u);
  return (ushort_t)(r >> 16);
}

__device__ __forceinline__ float fast_exp2(float x) {
#if __has_builtin(__builtin_amdgcn_exp2f)
  return __builtin_amdgcn_exp2f(x);
#else
  return exp2f(x);
#endif
}

// ---------------- amax: x + 4 weights in one dispatch ----------------
__device__ __forceinline__ void amax_reduce_store(float m, unsigned* slot) {
  __shared__ float wred[4];
  int wv = threadIdx.x >> 6, lane = threadIdx.x & 63;
#pragma unroll
  for (int off = 32; off > 0; off >>= 1) m = fmaxf(m, __shfl_down(m, off));
  if (lane == 0) wred[wv] = m;
  __syncthreads();
  if (threadIdx.x == 0) {
    float r = fmaxf(fmaxf(wred[0], wred[1]), fmaxf(wred[2], wred[3]));
    atomicMax(slot, __float_as_uint(r));
  }
}

__global__ __launch_bounds__(256) void amax5_kernel(
    const float* __restrict__ x, const float* w0, const float* w1,
    const float* w2, const float* w3, int n4x, int n4w,
    unsigned* __restrict__ slots) {
  int y = blockIdx.y;
  const float* p = (y == 0) ? x : (y == 1) ? w0 : (y == 2) ? w1 : (y == 3) ? w2 : w3;
  int n4 = (y == 0) ? n4x : n4w;
  const float4* x4 = (const float4*)p;
  float m = 0.f;
  for (int i = blockIdx.x * blockDim.x + threadIdx.x; i < n4; i += gridDim.x * blockDim.x) {
    float4 v = x4[i];
    m = fmaxf(m, fmaxf(fmaxf(fabsf(v.x), fabsf(v.y)), fmaxf(fabsf(v.z), fabsf(v.w))));
  }
  amax_reduce_store(m, slots + y);
}

// ------- quantize weights: integer codes round(w/s), stored exactly as bf16 -------
__global__ __launch_bounds__(256) void quant4_kernel(const float* w0, const float* w1,
                                                     const float* w2, const float* w3,
                                                     ushort_t* q0, ushort_t* q1,
                                                     ushort_t* q2, ushort_t* q3,
                                                     int n4, const unsigned* __restrict__ slots) {
  int y = blockIdx.y;
  const float* x = (y == 0) ? w0 : (y == 1) ? w1 : (y == 2) ? w2 : w3;
  ushort_t* qc = (y == 0) ? q0 : (y == 1) ? q1 : (y == 2) ? q2 : q3;
  float amax = __uint_as_float(slots[y + 1]);
  float s = fmaxf(amax / 127.0f, 1e-8f);
  float inv = 1.0f / s;
  const float4* x4 = (const float4*)x;
  ushort4* q4 = (ushort4*)qc;
  for (int i = blockIdx.x * blockDim.x + threadIdx.x; i < n4; i += gridDim.x * blockDim.x) {
    float4 v = x4[i];
    ushort4 o;
    o.x = f2bf(rintf(v.x * inv));
    o.y = f2bf(rintf(v.y * inv));
    o.z = f2bf(rintf(v.z * inv));
    o.w = f2bf(rintf(v.w * inv));
    q4[i] = o;
  }
}

// ------- fused: quantize activations (one read of x) + LoRA t = x @ A^T -------
template <int NL>
__global__ __launch_bounds__(256) void lora_quant_kernel(
    const float* __restrict__ x, const unsigned* __restrict__ slot,
    ushort_t* __restrict__ xc,
    const float* __restrict__ A0, const float* __restrict__ A1, const float* __restrict__ A2,
    float* __restrict__ t0, float* __restrict__ t1, float* __restrict__ t2) {
  const int row = blockIdx.x;
  const int tid = threadIdx.x;
  const int k0 = tid * 4;
  float amax = __uint_as_float(*slot);
  float s = fmaxf(amax / 127.0f, 1e-8f);
  float inv = 1.0f / s;

  float4 xv = *(const float4*)&x[(size_t)row * DIM + k0];
  ushort4 qo;
  qo.x = f2bf(rintf(xv.x * inv));
  qo.y = f2bf(rintf(xv.y * inv));
  qo.z = f2bf(rintf(xv.z * inv));
  qo.w = f2bf(rintf(xv.w * inv));
  *(ushort4*)&xc[(size_t)row * DIM + k0] = qo;

  float p[NL * 8];
#pragma unroll
  for (int r = 0; r < 8; r++) {
    float4 a = *(const float4*)&A0[r * DIM + k0];
    p[r] = xv.x * a.x + xv.y * a.y + xv.z * a.z + xv.w * a.w;
    if (NL > 1) {
      float4 a1 = *(const float4*)&A1[r * DIM + k0];
      p[8 + r] = xv.x * a1.x + xv.y * a1.y + xv.z * a1.z + xv.w * a1.w;
    }
    if (NL > 2) {
      float4 a2 = *(const float4*)&A2[r * DIM + k0];
      p[16 + r] = xv.x * a2.x + xv.y * a2.y + xv.z * a2.z + xv.w * a2.w;
    }
  }
#pragma unroll
  for (int j = 0; j < NL * 8; j++) {
    float v = p[j];
#pragma unroll
    for (int off = 32; off > 0; off >>= 1) v += __shfl_down(v, off);
    p[j] = v;
  }
  __shared__ float red[4][24];
  int wv = tid >> 6, lane = tid & 63;
  if (lane == 0) {
#pragma unroll
    for (int j = 0; j < NL * 8; j++) red[wv][j] = p[j];
  }
  __syncthreads();
  if (tid < NL * 8) {
    int j = tid;
    float sv = red[0][j] + red[1][j] + red[2][j] + red[3][j];
    float* tp = (j < 8) ? t0 : ((j < 16) ? t1 : t2);
    tp[(size_t)row * 8 + (j & 7)] = sv;
  }
}

// ---------------- projection GEMM on integer codes (exact) ----------------
template <bool BF16OUT, int BN>
__device__ __forceinline__ void proj_body(
    const ushort_t* __restrict__ Ac, const ushort_t* __restrict__ Wc,
    const unsigned* __restrict__ sxslot, const unsigned* __restrict__ swslot,
    const float* __restrict__ bias, const float* __restrict__ t,
    const float* __restrict__ Bl, void* __restrict__ Cout,
    int m0, int n0) {
  __shared__ alignas(16) ushort_t As[128 * 64];
  __shared__ alignas(16) ushort_t Bs[BN * 64];
  __shared__ float Ts[128 * 8];
  __shared__ float Bls[BN * 8];
  __shared__ float biass[BN];

  const int tid = threadIdx.x;
  constexpr int NJ = BN / 32;
  constexpr int BITS = BN * 8 / 256;

  for (int i = tid; i < 128 * 8; i += 256) Ts[i] = t[(size_t)m0 * 8 + i];
  for (int i = tid; i < BN * 8; i += 256) Bls[i] = Bl[(size_t)n0 * 8 + i];
  if (tid < BN) biass[tid] = bias[n0 + tid];

  f32x4 acc[4][NJ];
#pragma unroll
  for (int i = 0; i < 4; i++)
#pragma unroll
    for (int j = 0; j < NJ; j++) {
      acc[i][j][0] = 0.f; acc[i][j][1] = 0.f; acc[i][j][2] = 0.f; acc[i][j][3] = 0.f;
    }

  const int wv = tid >> 6, lane = tid & 63;
  const int wr = wv >> 1, wc = wv & 1;
  const int l15 = lane & 15, hi = lane >> 4;

  for (int kt = 0; kt < 16; kt++) {
    const int k0 = kt * 64;
#pragma unroll
    for (int it = 0; it < 4; it++) {
      int idx = it * 256 + tid;
      int r = idx >> 3, c = idx & 7;
      *(int4*)&As[r * 64 + (c ^ (r & 7)) * 8] = *(const int4*)&Ac[(size_t)(m0 + r) * DIM + k0 + c * 8];
    }
#pragma unroll
    for (int it = 0; it < BITS; it++) {
      int idx = it * 256 + tid;
      int r = idx >> 3, c = idx & 7;
      *(int4*)&Bs[r * 64 + (c ^ (r & 7)) * 8] = *(const int4*)&Wc[(size_t)(n0 + r) * DIM + k0 + c * 8];
    }
    __syncthreads();
#pragma unroll
    for (int ks = 0; ks < 2; ks++) {
      short8 a[4], b[NJ];
#pragma unroll
      for (int i = 0; i < 4; i++) {
        int row = wr * 64 + i * 16 + l15;
        a[i] = *(const short8*)&As[row * 64 + ((ks * 4 + hi) ^ (row & 7)) * 8];
      }
#pragma unroll
      for (int j = 0; j < NJ; j++) {
        int col = wc * (BN / 2) + j * 16 + l15;
        b[j] = *(const short8*)&Bs[col * 64 + ((ks * 4 + hi) ^ (col & 7)) * 8];
      }
      __builtin_amdgcn_s_setprio(1);
#pragma unroll
      for (int i = 0; i < 4; i++)
#pragma unroll
        for (int j = 0; j < NJ; j++)
          acc[i][j] = __builtin_amdgcn_mfma_f32_16x16x32_bf16(a[i], b[j], acc[i][j], 0, 0, 0);
      __builtin_amdgcn_s_setprio(0);
    }
    __syncthreads();
  }

  float sx = fmaxf(__uint_as_float(*sxslot) / 127.0f, 1e-8f);
  float sw = fmaxf(__uint_as_float(*swslot) / 127.0f, 1e-8f);
  float ss = sx * sw;
#pragma unroll
  for (int i = 0; i < 4; i++) {
#pragma unroll
    for (int rr = 0; rr < 4; rr++) {
      int rl = wr * 64 + i * 16 + hi * 4 + rr;
      float tv[8];
#pragma unroll
      for (int q = 0; q < 8; q++) tv[q] = Ts[rl * 8 + q];
#pragma unroll
      for (int j = 0; j < NJ; j++) {
        int cl = wc * (BN / 2) + j * 16 + l15;
        float lr = 0.f;
#pragma unroll
        for (int q = 0; q < 8; q++) lr += tv[q] * Bls[cl * 8 + q];
        float val = acc[i][j][rr] * ss + biass[cl] + 2.0f * lr;
        if (BF16OUT)
          ((ushort_t*)Cout)[(size_t)(m0 + rl) * DIM + n0 + cl] = f2bf(val);
        else
          ((float*)Cout)[(size_t)(m0 + rl) * DIM + n0 + cl] = val;
      }
    }
  }
}

struct ProjSet {
  const ushort_t* W; const unsigned* sw; const float* bias;
  const float* t; const float* Bl; ushort_t* out;
};

__global__ __launch_bounds__(256) void proj_qkv_kernel(
    const ushort_t* __restrict__ Ac, const unsigned* __restrict__ sxslot,
    ProjSet pq, ProjSet pk, ProjSet pv) {
  ProjSet P = (blockIdx.z == 0) ? pq : (blockIdx.z == 1) ? pk : pv;
  proj_body<true, 128>(Ac, P.W, sxslot, P.sw, P.bias, P.t, P.Bl, P.out,
                       blockIdx.y * 128, blockIdx.x * 128);
}

__global__ __launch_bounds__(256) void proj_out_kernel(
    const ushort_t* __restrict__ Ac, const ushort_t* __restrict__ Wc,
    const unsigned* __restrict__ sxslot, const unsigned* __restrict__ swslot,
    const float* __restrict__ bias, const float* __restrict__ t,
    const float* __restrict__ Bl, float* __restrict__ Cout) {
  proj_body<false, 64>(Ac, Wc, sxslot, swslot, bias, t, Bl, Cout,
                       blockIdx.y * 128, blockIdx.x * 64);
}

// ---- V transpose, 256-thread LDS-tiled: vb[token][1024] bf16 -> vT[bh*64+d][2048] ----
__global__ __launch_bounds__(256) void vtrans_kernel(const ushort_t* __restrict__ vb,
                                                     ushort_t* __restrict__ vT) {
  __shared__ alignas(16) ushort_t Lt[64 * 72];
  const int s0 = blockIdx.x * 64;
  const int bh = blockIdx.y;
  const int b = bh >> 4, h = bh & 15;
  const int tid = threadIdx.x;
#pragma unroll
  for (int it = 0; it < 2; it++) {
    int g = it * 256 + tid;
    int r = g >> 3, c = g & 7;
    *(int4*)&Lt[r * 72 + c * 8] =
        *(const int4*)&vb[(size_t)(b * SEQ + s0 + r) * DIM + h * 64 + c * 8];
  }
  __syncthreads();
#pragma unroll
  for (int it = 0; it < 2; it++) {
    int g = it * 256 + tid;
    int d = g >> 3, c = g & 7;
    union { int4 v; ushort_t u[8]; } out;
#pragma unroll
    for (int j = 0; j < 8; j++) out.u[j] = Lt[(c * 8 + j) * 72 + d];
    *(int4*)&vT[((size_t)bh * 64 + d) * SEQ + s0 + c * 8] = out.v;
  }
}

// ------- flash attention v6: double-buffered LDS, ONE barrier per tile -------
// (T14 done right: issue loads early, compute overlaps latency, write after compute)
__global__ __launch_bounds__(256) void attn6_kernel(
    const ushort_t* __restrict__ qb, const ushort_t* __restrict__ kb,
    const ushort_t* __restrict__ vT, const float* __restrict__ mask,
    float* __restrict__ obuf, unsigned* __restrict__ amax_slot) {
  __shared__ alignas(16) ushort_t Ks[2][64 * 64];
  __shared__ alignas(16) ushort_t Vs[2][64 * 64];   // Vs[d][key]
  __shared__ alignas(16) ushort_t Ps[128 * 72];
  __shared__ float maskv[2][64];
  __shared__ float wmax[4];

  const float LOG2E = 1.44269504088896f;
  const float SCL2 = 0.125f * LOG2E;
  const float THR2 = 8.0f * LOG2E;

  // 512 blocks; XCD swizzle: 64 consecutive logicals per XCD
  const int lin = blockIdx.x;
  const int logical = (lin & 7) * 64 + (lin >> 3);
  const int bh = logical >> 4;
  const int qt = logical & 15;
  const int b = bh >> 4, h = bh & 15;
  const size_t tokbase = (size_t)b * SEQ;
  const int q0 = qt * 128;

  const int tid = threadIdx.x;
  const int wv = tid >> 6, lane = tid & 63, l15 = lane & 15, hi = lane >> 4;
  const int sr = tid >> 3, sc = tid & 7;          // staging row/col (per it offset +32 rows)
  const int sslot = (sc ^ (sr & 7)) * 8;
  const int sslot2 = (sc ^ ((sr + 32) & 7)) * 8;

  short8 qf[2][2];
#pragma unroll
  for (int rb = 0; rb < 2; rb++)
#pragma unroll
    for (int ks = 0; ks < 2; ks++) {
      int row = q0 + wv * 32 + rb * 16 + l15;
      qf[rb][ks] = *(const short8*)&qb[(tokbase + row) * DIM + h * 64 + ks * 32 + hi * 8];
    }

  float mo[2][4], ls[2][4];
  f32x4 o[2][4];
#pragma unroll
  for (int rb = 0; rb < 2; rb++)
#pragma unroll
    for (int r = 0; r < 4; r++) { mo[rb][r] = -1e30f; ls[rb][r] = 0.f; }
#pragma unroll
  for (int rb = 0; rb < 2; rb++)
#pragma unroll
    for (int d = 0; d < 4; d++) { o[rb][d][0] = 0.f; o[rb][d][1] = 0.f; o[rb][d][2] = 0.f; o[rb][d][3] = 0.f; }

  // prologue: load + stage tile 0 into buffer 0
  int4 kpre0, kpre1, vpre0, vpre1;
  float mpre;
  kpre0 = *(const int4*)&kb[(tokbase + sr) * DIM + h * 64 + sc * 8];
  vpre0 = *(const int4*)&vT[((size_t)bh * 64 + sr) * SEQ + sc * 8];
  kpre1 = *(const int4*)&kb[(tokbase + sr + 32) * DIM + h * 64 + sc * 8];
  vpre1 = *(const int4*)&vT[((size_t)bh * 64 + sr + 32) * SEQ + sc * 8];
  mpre = (tid < 64) ? (1.0f - mask[tokbase + tid]) * (-10000.0f * LOG2E) : 0.f;
  *(int4*)&Ks[0][sr * 64 + sslot] = kpre0;
  *(int4*)&Vs[0][sr * 64 + sslot] = vpre0;
  *(int4*)&Ks[0][(sr + 32) * 64 + sslot2] = kpre1;
  *(int4*)&Vs[0][(sr + 32) * 64 + sslot2] = vpre1;
  if (tid < 64) maskv[0][tid] = mpre;
  __syncthreads();

  for (int kt = 0; kt < 32; kt++) {
    const int cur = kt & 1, nxt = cur ^ 1;

    // issue next tile's global loads FIRST (latency overlaps compute below)
    if (kt < 31) {
      const int k0n = (kt + 1) * 64;
      kpre0 = *(const int4*)&kb[(tokbase + k0n + sr) * DIM + h * 64 + sc * 8];
      vpre0 = *(const int4*)&vT[((size_t)bh * 64 + sr) * SEQ + k0n + sc * 8];
      kpre1 = *(const int4*)&kb[(tokbase + k0n + sr + 32) * DIM + h * 64 + sc * 8];
      vpre1 = *(const int4*)&vT[((size_t)bh * 64 + sr + 32) * SEQ + k0n + sc * 8];
      if (tid < 64) mpre = (1.0f - mask[tokbase + k0n + tid]) * (-10000.0f * LOG2E);
    }

    // S = Q K^T (base-2 domain) from buf[cur]
    f32x4 s[2][4];
#pragma unroll
    for (int rb = 0; rb < 2; rb++)
#pragma unroll
      for (int cb = 0; cb < 4; cb++) { s[rb][cb][0] = 0.f; s[rb][cb][1] = 0.f; s[rb][cb][2] = 0.f; s[rb][cb][3] = 0.f; }
#pragma unroll
    for (int ks = 0; ks < 2; ks++) {
      short8 kf[4];
#pragma unroll
      for (int cb = 0; cb < 4; cb++) {
        int row = cb * 16 + l15;
        kf[cb] = *(const short8*)&Ks[cur][row * 64 + (((ks * 4 + hi) ^ (row & 7))) * 8];
      }
      __builtin_amdgcn_s_setprio(1);
#pragma unroll
      for (int rb = 0; rb < 2; rb++)
#pragma unroll
        for (int cb = 0; cb < 4; cb++)
          s[rb][cb] = __builtin_amdgcn_mfma_f32_16x16x32_bf16(qf[rb][ks], kf[cb], s[rb][cb], 0, 0, 0);
      __builtin_amdgcn_s_setprio(0);
    }
#pragma unroll
    for (int rb = 0; rb < 2; rb++)
#pragma unroll
      for (int cb = 0; cb < 4; cb++) {
        float mk = maskv[cur][cb * 16 + l15];
#pragma unroll
        for (int r = 0; r < 4; r++) s[rb][cb][r] = s[rb][cb][r] * SCL2 + mk;
      }

    // online softmax, base-2, defer-max (T13)
    float tmv[2][4];
    bool need = false;
#pragma unroll
    for (int rb = 0; rb < 2; rb++)
#pragma unroll
      for (int r = 0; r < 4; r++) {
        float tm = fmaxf(fmaxf(s[rb][0][r], s[rb][1][r]), fmaxf(s[rb][2][r], s[rb][3][r]));
#pragma unroll
        for (int mm = 1; mm < 16; mm <<= 1) tm = fmaxf(tm, __shfl_xor(tm, mm));
        tmv[rb][r] = tm;
        need = need || (tm > mo[rb][r] + THR2);
      }
    if (__any(need)) {
#pragma unroll
      for (int rb = 0; rb < 2; rb++)
#pragma unroll
        for (int r = 0; r < 4; r++) {
          float mn = fmaxf(mo[rb][r], tmv[rb][r]);
          float al = fast_exp2(mo[rb][r] - mn);
          mo[rb][r] = mn;
          ls[rb][r] *= al;
#pragma unroll
          for (int d = 0; d < 4; d++) o[rb][d][r] *= al;
        }
    }
    float rs[2][4];
#pragma unroll
    for (int rb = 0; rb < 2; rb++)
#pragma unroll
      for (int r = 0; r < 4; r++) rs[rb][r] = 0.f;
#pragma unroll
    for (int rb = 0; rb < 2; rb++)
#pragma unroll
      for (int cb = 0; cb < 4; cb++)
#pragma unroll
        for (int r = 0; r < 4; r++) {
          float pv = fast_exp2(s[rb][cb][r] - mo[rb][r]);
          s[rb][cb][r] = pv;
          rs[rb][r] += pv;
        }
#pragma unroll
    for (int rb = 0; rb < 2; rb++)
#pragma unroll
      for (int r = 0; r < 4; r++) {
        float v = rs[rb][r];
#pragma unroll
        for (int mm = 1; mm < 16; mm <<= 1) v += __shfl_xor(v, mm);
        ls[rb][r] += v;
      }
    // P -> LDS (wave-private rows, no barrier needed)
#pragma unroll
    for (int rb = 0; rb < 2; rb++)
#pragma unroll
      for (int cb = 0; cb < 4; cb++)
#pragma unroll
        for (int r = 0; r < 4; r++)
          Ps[(wv * 32 + rb * 16 + hi * 4 + r) * 72 + cb * 16 + l15] = f2bf(s[rb][cb][r]);
    // O += P V from buf[cur]
#pragma unroll
    for (int ks = 0; ks < 2; ks++) {
      short8 pf[2];
#pragma unroll
      for (int rb = 0; rb < 2; rb++) {
        int row = wv * 32 + rb * 16 + l15;
        pf[rb] = *(const short8*)&Ps[row * 72 + ks * 32 + hi * 8];
      }
      short8 vf[4];
#pragma unroll
      for (int db = 0; db < 4; db++) {
        int row = db * 16 + l15;
        vf[db] = *(const short8*)&Vs[cur][row * 64 + (((ks * 4 + hi) ^ (row & 7))) * 8];
      }
      __builtin_amdgcn_s_setprio(1);
#pragma unroll
      for (int rb = 0; rb < 2; rb++)
#pragma unroll
        for (int db = 0; db < 4; db++)
          o[rb][db] = __builtin_amdgcn_mfma_f32_16x16x32_bf16(pf[rb], vf[db], o[rb][db], 0, 0, 0);
      __builtin_amdgcn_s_setprio(0);
    }

    // write prefetched tile into buf[nxt] (safe: barrier below orders vs next reads;
    // barrier at top of THIS iter guaranteed all waves left buf[nxt]'s last use)
    if (kt < 31) {
      *(int4*)&Ks[nxt][sr * 64 + sslot] = kpre0;
      *(int4*)&Vs[nxt][sr * 64 + sslot] = vpre0;
      *(int4*)&Ks[nxt][(sr + 32) * 64 + sslot2] = kpre1;
      *(int4*)&Vs[nxt][(sr + 32) * 64 + sslot2] = vpre1;
      if (tid < 64) maskv[nxt][tid] = mpre;
    }
    __syncthreads();   // ONE barrier per tile
  }

  // epilogue: write O, fused amax
  float am = 0.f;
#pragma unroll
  for (int rb = 0; rb < 2; rb++)
#pragma unroll
    for (int r = 0; r < 4; r++) {
      float inv = 1.0f / ls[rb][r];
      size_t row = tokbase + q0 + wv * 32 + rb * 16 + hi * 4 + r;
#pragma unroll
      for (int db = 0; db < 4; db++) {
        float val = o[rb][db][r] * inv;
        am = fmaxf(am, fabsf(val));
        obuf[row * DIM + h * 64 + db * 16 + l15] = val;
      }
    }
#pragma unroll
  for (int off = 32; off > 0; off >>= 1) am = fmaxf(am, __shfl_down(am, off));
  if (lane == 0) wmax[wv] = am;
  __syncthreads();
  if (tid == 0)
    atomicMax(amax_slot, __float_as_uint(fmaxf(fmaxf(wmax[0], wmax[1]), fmaxf(wmax[2], wmax[3]))));
}

// ---------------- launcher ----------------
extern "C" void kernel_launch(void* const* d_in, const int* in_sizes, int n_in,
                              void* d_out, int out_size, void* d_ws, size_t ws_size,
                              hipStream_t stream) {
  const float* x     = (const float*)d_in[0];
  const float* mask  = (const float*)d_in[1];
  const float* q_W   = (const float*)d_in[2];
  const float* q_b   = (const float*)d_in[3];
  const float* q_A   = (const float*)d_in[4];
  const float* q_B   = (const float*)d_in[5];
  const float* k_W   = (const float*)d_in[6];
  const float* k_b   = (const float*)d_in[7];
  const float* k_A   = (const float*)d_in[8];
  const float* k_B   = (const float*)d_in[9];
  const float* v_W   = (const float*)d_in[10];
  const float* v_b   = (const float*)d_in[11];
  const float* v_A   = (const float*)d_in[12];
  const float* v_B   = (const float*)d_in[13];
  const float* o_W   = (const float*)d_in[14];
  const float* o_b   = (const float*)d_in[15];
  const float* o_A   = (const float*)d_in[16];
  const float* o_B   = (const float*)d_in[17];
  float* out = (float*)d_out;

  char* ws = (char*)d_ws;
  const size_t MB = 1u << 20;
  unsigned* slots = (unsigned*)ws;                  // 6 amax slots
  float* t_q = (float*)(ws + 4096);
  float* t_k = t_q + MROWS * 8;
  float* t_v = t_k + MROWS * 8;
  float* t_o = t_v + MROWS * 8;
  ushort_t* xc  = (ushort_t*)(ws + 1 * MB);
  ushort_t* qWc = (ushort_t*)(ws + 9 * MB);
  ushort_t* kWc = (ushort_t*)(ws + 11 * MB);
  ushort_t* vWc = (ushort_t*)(ws + 13 * MB);
  ushort_t* oWc = (ushort_t*)(ws + 15 * MB);
  ushort_t* qbb = (ushort_t*)(ws + 17 * MB);
  ushort_t* kbb = (ushort_t*)(ws + 25 * MB);
  ushort_t* vbb = (ushort_t*)(ws + 33 * MB);
  ushort_t* vTb = (ushort_t*)(ws + 41 * MB);
  float*    abuf = (float*)(ws + 49 * MB);
  ushort_t* ac  = (ushort_t*)(ws + 65 * MB);

  (void)hipMemsetAsync(ws, 0, 64, stream);

  const int NX4 = (MROWS * DIM) / 4;
  const int NW4 = (DIM * DIM) / 4;

  amax5_kernel<<<dim3(256, 5), 256, 0, stream>>>(x, q_W, k_W, v_W, o_W, NX4, NW4, slots);
  quant4_kernel<<<dim3(128, 4), 256, 0, stream>>>(q_W, k_W, v_W, o_W,
                                                  qWc, kWc, vWc, oWc, NW4, slots);

  lora_quant_kernel<3><<<MROWS, 256, 0, stream>>>(x, slots + 0, xc, q_A, k_A, v_A,
                                                  t_q, t_k, t_v);

  ProjSet pq = { qWc, slots + 1, q_b, t_q, q_B, qbb };
  ProjSet pk = { kWc, slots + 2, k_b, t_k, k_B, kbb };
  ProjSet pv = { vWc, slots + 3, v_b, t_v, v_B, vbb };
  proj_qkv_kernel<<<dim3(DIM / 128, MROWS / 128, 3), 256, 0, stream>>>(xc, slots + 0, pq, pk, pv);

  vtrans_kernel<<<dim3(SEQ / 64, BSZ * NHEAD), 256, 0, stream>>>(vbb, vTb);

  attn6_kernel<<<512, 256, 0, stream>>>(qbb, kbb, vTb, mask, abuf, slots + 5);

  lora_quant_kernel<1><<<MROWS, 256, 0, stream>>>(abuf, slots + 5, ac, o_A, nullptr, nullptr,
                                                  t_o, nullptr, nullptr);

  proj_out_kernel<<<dim3(DIM / 64, MROWS / 128), 256, 0, stream>>>(
      ac, oWc, slots + 5, slots + 4, o_b, t_o, o_B, out);
}

// Round 8
// 231.304 us; speedup vs baseline: 1.3829x; 1.1575x over previous
//
#include <hip/hip_runtime.h>
#include <stdint.h>

typedef __attribute__((ext_vector_type(8))) short short8;
typedef __attribute__((ext_vector_type(4))) float f32x4;
typedef unsigned short ushort_t;

#define SEQ   2048
#define BSZ   2
#define DIM   1024
#define NHEAD 16
#define HDIM  64
#define MROWS (BSZ*SEQ)   // 4096

__device__ __forceinline__ ushort_t f2bf(float f) {
  unsigned u = __float_as_uint(f);
  unsigned r = u + 0x7fffu + ((u >> 16) & 1u);
  return (ushort_t)(r >> 16);
}
__device__ __forceinline__ unsigned pack2(float a, float b) {
  return (unsigned)f2bf(a) | ((unsigned)f2bf(b) << 16);
}

__device__ __forceinline__ float fast_exp2(float x) {
#if __has_builtin(__builtin_amdgcn_exp2f)
  return __builtin_amdgcn_exp2f(x);
#else
  return exp2f(x);
#endif
}

// ---------------- amax: x + 4 weights in one dispatch ----------------
__device__ __forceinline__ void amax_reduce_store(float m, unsigned* slot) {
  __shared__ float wred[4];
  int wv = threadIdx.x >> 6, lane = threadIdx.x & 63;
#pragma unroll
  for (int off = 32; off > 0; off >>= 1) m = fmaxf(m, __shfl_down(m, off));
  if (lane == 0) wred[wv] = m;
  __syncthreads();
  if (threadIdx.x == 0) {
    float r = fmaxf(fmaxf(wred[0], wred[1]), fmaxf(wred[2], wred[3]));
    atomicMax(slot, __float_as_uint(r));
  }
}

__global__ __launch_bounds__(256) void amax5_kernel(
    const float* __restrict__ x, const float* w0, const float* w1,
    const float* w2, const float* w3, int n4x, int n4w,
    unsigned* __restrict__ slots) {
  int y = blockIdx.y;
  const float* p = (y == 0) ? x : (y == 1) ? w0 : (y == 2) ? w1 : (y == 3) ? w2 : w3;
  int n4 = (y == 0) ? n4x : n4w;
  const float4* x4 = (const float4*)p;
  float m = 0.f;
  for (int i = blockIdx.x * blockDim.x + threadIdx.x; i < n4; i += gridDim.x * blockDim.x) {
    float4 v = x4[i];
    m = fmaxf(m, fmaxf(fmaxf(fabsf(v.x), fabsf(v.y)), fmaxf(fabsf(v.z), fabsf(v.w))));
  }
  amax_reduce_store(m, slots + y);
}

// ------- quantize weights: integer codes round(w/s), stored exactly as bf16 -------
__global__ __launch_bounds__(256) void quant4_kernel(const float* w0, const float* w1,
                                                     const float* w2, const float* w3,
                                                     ushort_t* q0, ushort_t* q1,
                                                     ushort_t* q2, ushort_t* q3,
                                                     int n4, const unsigned* __restrict__ slots) {
  int y = blockIdx.y;
  const float* x = (y == 0) ? w0 : (y == 1) ? w1 : (y == 2) ? w2 : w3;
  ushort_t* qc = (y == 0) ? q0 : (y == 1) ? q1 : (y == 2) ? q2 : q3;
  float amax = __uint_as_float(slots[y + 1]);
  float s = fmaxf(amax / 127.0f, 1e-8f);
  float inv = 1.0f / s;
  const float4* x4 = (const float4*)x;
  ushort4* q4 = (ushort4*)qc;
  for (int i = blockIdx.x * blockDim.x + threadIdx.x; i < n4; i += gridDim.x * blockDim.x) {
    float4 v = x4[i];
    ushort4 o;
    o.x = f2bf(rintf(v.x * inv));
    o.y = f2bf(rintf(v.y * inv));
    o.z = f2bf(rintf(v.z * inv));
    o.w = f2bf(rintf(v.w * inv));
    q4[i] = o;
  }
}

// ------- fused: quantize activations (one read of x) + LoRA t = x @ A^T -------
template <int NL>
__global__ __launch_bounds__(256) void lora_quant_kernel(
    const float* __restrict__ x, const unsigned* __restrict__ slot,
    ushort_t* __restrict__ xc,
    const float* __restrict__ A0, const float* __restrict__ A1, const float* __restrict__ A2,
    float* __restrict__ t0, float* __restrict__ t1, float* __restrict__ t2) {
  const int row = blockIdx.x;
  const int tid = threadIdx.x;
  const int k0 = tid * 4;
  float amax = __uint_as_float(*slot);
  float s = fmaxf(amax / 127.0f, 1e-8f);
  float inv = 1.0f / s;

  float4 xv = *(const float4*)&x[(size_t)row * DIM + k0];
  ushort4 qo;
  qo.x = f2bf(rintf(xv.x * inv));
  qo.y = f2bf(rintf(xv.y * inv));
  qo.z = f2bf(rintf(xv.z * inv));
  qo.w = f2bf(rintf(xv.w * inv));
  *(ushort4*)&xc[(size_t)row * DIM + k0] = qo;

  float p[NL * 8];
#pragma unroll
  for (int r = 0; r < 8; r++) {
    float4 a = *(const float4*)&A0[r * DIM + k0];
    p[r] = xv.x * a.x + xv.y * a.y + xv.z * a.z + xv.w * a.w;
    if (NL > 1) {
      float4 a1 = *(const float4*)&A1[r * DIM + k0];
      p[8 + r] = xv.x * a1.x + xv.y * a1.y + xv.z * a1.z + xv.w * a1.w;
    }
    if (NL > 2) {
      float4 a2 = *(const float4*)&A2[r * DIM + k0];
      p[16 + r] = xv.x * a2.x + xv.y * a2.y + xv.z * a2.z + xv.w * a2.w;
    }
  }
#pragma unroll
  for (int j = 0; j < NL * 8; j++) {
    float v = p[j];
#pragma unroll
    for (int off = 32; off > 0; off >>= 1) v += __shfl_down(v, off);
    p[j] = v;
  }
  __shared__ float red[4][24];
  int wv = tid >> 6, lane = tid & 63;
  if (lane == 0) {
#pragma unroll
    for (int j = 0; j < NL * 8; j++) red[wv][j] = p[j];
  }
  __syncthreads();
  if (tid < NL * 8) {
    int j = tid;
    float sv = red[0][j] + red[1][j] + red[2][j] + red[3][j];
    float* tp = (j < 8) ? t0 : ((j < 16) ? t1 : t2);
    tp[(size_t)row * 8 + (j & 7)] = sv;
  }
}

// ---------------- projection GEMM on integer codes (exact) ----------------
template <bool BF16OUT, int BN>
__device__ __forceinline__ void proj_body(
    const ushort_t* __restrict__ Ac, const ushort_t* __restrict__ Wc,
    const unsigned* __restrict__ sxslot, const unsigned* __restrict__ swslot,
    const float* __restrict__ bias, const float* __restrict__ t,
    const float* __restrict__ Bl, void* __restrict__ Cout,
    int m0, int n0) {
  __shared__ alignas(16) ushort_t As[128 * 64];
  __shared__ alignas(16) ushort_t Bs[BN * 64];
  __shared__ float Ts[128 * 8];
  __shared__ float Bls[BN * 8];
  __shared__ float biass[BN];

  const int tid = threadIdx.x;
  constexpr int NJ = BN / 32;
  constexpr int BITS = BN * 8 / 256;

  for (int i = tid; i < 128 * 8; i += 256) Ts[i] = t[(size_t)m0 * 8 + i];
  for (int i = tid; i < BN * 8; i += 256) Bls[i] = Bl[(size_t)n0 * 8 + i];
  if (tid < BN) biass[tid] = bias[n0 + tid];

  f32x4 acc[4][NJ];
#pragma unroll
  for (int i = 0; i < 4; i++)
#pragma unroll
    for (int j = 0; j < NJ; j++) {
      acc[i][j][0] = 0.f; acc[i][j][1] = 0.f; acc[i][j][2] = 0.f; acc[i][j][3] = 0.f;
    }

  const int wv = tid >> 6, lane = tid & 63;
  const int wr = wv >> 1, wc = wv & 1;
  const int l15 = lane & 15, hi = lane >> 4;

  for (int kt = 0; kt < 16; kt++) {
    const int k0 = kt * 64;
#pragma unroll
    for (int it = 0; it < 4; it++) {
      int idx = it * 256 + tid;
      int r = idx >> 3, c = idx & 7;
      *(int4*)&As[r * 64 + (c ^ (r & 7)) * 8] = *(const int4*)&Ac[(size_t)(m0 + r) * DIM + k0 + c * 8];
    }
#pragma unroll
    for (int it = 0; it < BITS; it++) {
      int idx = it * 256 + tid;
      int r = idx >> 3, c = idx & 7;
      *(int4*)&Bs[r * 64 + (c ^ (r & 7)) * 8] = *(const int4*)&Wc[(size_t)(n0 + r) * DIM + k0 + c * 8];
    }
    __syncthreads();
#pragma unroll
    for (int ks = 0; ks < 2; ks++) {
      short8 a[4], b[NJ];
#pragma unroll
      for (int i = 0; i < 4; i++) {
        int row = wr * 64 + i * 16 + l15;
        a[i] = *(const short8*)&As[row * 64 + ((ks * 4 + hi) ^ (row & 7)) * 8];
      }
#pragma unroll
      for (int j = 0; j < NJ; j++) {
        int col = wc * (BN / 2) + j * 16 + l15;
        b[j] = *(const short8*)&Bs[col * 64 + ((ks * 4 + hi) ^ (col & 7)) * 8];
      }
      __builtin_amdgcn_s_setprio(1);
#pragma unroll
      for (int i = 0; i < 4; i++)
#pragma unroll
        for (int j = 0; j < NJ; j++)
          acc[i][j] = __builtin_amdgcn_mfma_f32_16x16x32_bf16(a[i], b[j], acc[i][j], 0, 0, 0);
      __builtin_amdgcn_s_setprio(0);
    }
    __syncthreads();
  }

  float sx = fmaxf(__uint_as_float(*sxslot) / 127.0f, 1e-8f);
  float sw = fmaxf(__uint_as_float(*swslot) / 127.0f, 1e-8f);
  float ss = sx * sw;
#pragma unroll
  for (int i = 0; i < 4; i++) {
#pragma unroll
    for (int rr = 0; rr < 4; rr++) {
      int rl = wr * 64 + i * 16 + hi * 4 + rr;
      float tv[8];
#pragma unroll
      for (int q = 0; q < 8; q++) tv[q] = Ts[rl * 8 + q];
#pragma unroll
      for (int j = 0; j < NJ; j++) {
        int cl = wc * (BN / 2) + j * 16 + l15;
        float lr = 0.f;
#pragma unroll
        for (int q = 0; q < 8; q++) lr += tv[q] * Bls[cl * 8 + q];
        float val = acc[i][j][rr] * ss + biass[cl] + 2.0f * lr;
        if (BF16OUT)
          ((ushort_t*)Cout)[(size_t)(m0 + rl) * DIM + n0 + cl] = f2bf(val);
        else
          ((float*)Cout)[(size_t)(m0 + rl) * DIM + n0 + cl] = val;
      }
    }
  }
}

struct ProjSet {
  const ushort_t* W; const unsigned* sw; const float* bias;
  const float* t; const float* Bl; ushort_t* out;
};

__global__ __launch_bounds__(256) void proj_qkv_kernel(
    const ushort_t* __restrict__ Ac, const unsigned* __restrict__ sxslot,
    ProjSet pq, ProjSet pk, ProjSet pv) {
  ProjSet P = (blockIdx.z == 0) ? pq : (blockIdx.z == 1) ? pk : pv;
  proj_body<true, 128>(Ac, P.W, sxslot, P.sw, P.bias, P.t, P.Bl, P.out,
                       blockIdx.y * 128, blockIdx.x * 128);
}

__global__ __launch_bounds__(256) void proj_out_kernel(
    const ushort_t* __restrict__ Ac, const ushort_t* __restrict__ Wc,
    const unsigned* __restrict__ sxslot, const unsigned* __restrict__ swslot,
    const float* __restrict__ bias, const float* __restrict__ t,
    const float* __restrict__ Bl, float* __restrict__ Cout) {
  proj_body<false, 64>(Ac, Wc, sxslot, swslot, bias, t, Bl, Cout,
                       blockIdx.y * 128, blockIdx.x * 64);
}

// ---- V transpose, 256-thread LDS-tiled: vb[token][1024] bf16 -> vT[bh*64+d][2048] ----
__global__ __launch_bounds__(256) void vtrans_kernel(const ushort_t* __restrict__ vb,
                                                     ushort_t* __restrict__ vT) {
  __shared__ alignas(16) ushort_t Lt[64 * 72];
  const int s0 = blockIdx.x * 64;
  const int bh = blockIdx.y;
  const int b = bh >> 4, h = bh & 15;
  const int tid = threadIdx.x;
#pragma unroll
  for (int it = 0; it < 2; it++) {
    int g = it * 256 + tid;
    int r = g >> 3, c = g & 7;
    *(int4*)&Lt[r * 72 + c * 8] =
        *(const int4*)&vb[(size_t)(b * SEQ + s0 + r) * DIM + h * 64 + c * 8];
  }
  __syncthreads();
#pragma unroll
  for (int it = 0; it < 2; it++) {
    int g = it * 256 + tid;
    int d = g >> 3, c = g & 7;
    union { int4 v; ushort_t u[8]; } out;
#pragma unroll
    for (int j = 0; j < 8; j++) out.u[j] = Lt[(c * 8 + j) * 72 + d];
    *(int4*)&vT[((size_t)bh * 64 + d) * SEQ + s0 + c * 8] = out.v;
  }
}

// ------- flash attention v7: swapped QK^T (T12-lite) + dbuf 1-barrier -------
// D[key][qrow]: lane holds 16 keys (kb x r) for qrow = rb*16 + l15.
// Row-reduce = in-lane 16 + shfl_xor(16,32). P-write = 8x ds_write_b64.
__global__ __launch_bounds__(256) void attn7_kernel(
    const ushort_t* __restrict__ qb, const ushort_t* __restrict__ kb,
    const ushort_t* __restrict__ vT, const float* __restrict__ mask,
    float* __restrict__ obuf, unsigned* __restrict__ amax_slot) {
  __shared__ alignas(16) ushort_t Ks[2][64 * 64];
  __shared__ alignas(16) ushort_t Vs[2][64 * 64];   // Vs[d][key]
  __shared__ alignas(16) ushort_t Ps[128 * 72];
  __shared__ alignas(16) float maskv[2][64];
  __shared__ float wmax[4];

  const float LOG2E = 1.44269504088896f;
  const float SCL2 = 0.125f * LOG2E;
  const float THR2 = 8.0f * LOG2E;

  // 512 blocks; XCD swizzle: 64 consecutive logicals per XCD
  const int lin = blockIdx.x;
  const int logical = (lin & 7) * 64 + (lin >> 3);
  const int bh = logical >> 4;
  const int qt = logical & 15;
  const int b = bh >> 4, h = bh & 15;
  const size_t tokbase = (size_t)b * SEQ;
  const int q0 = qt * 128;

  const int tid = threadIdx.x;
  const int wv = tid >> 6, lane = tid & 63, l15 = lane & 15, hi = lane >> 4;
  const int sr = tid >> 3, sc = tid & 7;
  const int sslot = (sc ^ (sr & 7)) * 8;
  const int sslot2 = (sc ^ ((sr + 32) & 7)) * 8;

  // Q fragments (now B-operand; same fragment layout as before)
  short8 qf[2][2];
#pragma unroll
  for (int rb = 0; rb < 2; rb++)
#pragma unroll
    for (int ks = 0; ks < 2; ks++) {
      int row = q0 + wv * 32 + rb * 16 + l15;
      qf[rb][ks] = *(const short8*)&qb[(tokbase + row) * DIM + h * 64 + ks * 32 + hi * 8];
    }

  // per-lane softmax state: qrow = q0 + wv*32 + rb*16 + l15 (uniform across hi)
  float mo[2], ls[2];
  f32x4 o[2][4];
#pragma unroll
  for (int rb = 0; rb < 2; rb++) { mo[rb] = -1e30f; ls[rb] = 0.f; }
#pragma unroll
  for (int rb = 0; rb < 2; rb++)
#pragma unroll
    for (int d = 0; d < 4; d++) { o[rb][d][0] = 0.f; o[rb][d][1] = 0.f; o[rb][d][2] = 0.f; o[rb][d][3] = 0.f; }

  // prologue: load + stage tile 0 into buffer 0
  int4 kpre0, kpre1, vpre0, vpre1;
  float mpre;
  kpre0 = *(const int4*)&kb[(tokbase + sr) * DIM + h * 64 + sc * 8];
  vpre0 = *(const int4*)&vT[((size_t)bh * 64 + sr) * SEQ + sc * 8];
  kpre1 = *(const int4*)&kb[(tokbase + sr + 32) * DIM + h * 64 + sc * 8];
  vpre1 = *(const int4*)&vT[((size_t)bh * 64 + sr + 32) * SEQ + sc * 8];
  mpre = (tid < 64) ? (1.0f - mask[tokbase + tid]) * (-10000.0f * LOG2E) : 0.f;
  *(int4*)&Ks[0][sr * 64 + sslot] = kpre0;
  *(int4*)&Vs[0][sr * 64 + sslot] = vpre0;
  *(int4*)&Ks[0][(sr + 32) * 64 + sslot2] = kpre1;
  *(int4*)&Vs[0][(sr + 32) * 64 + sslot2] = vpre1;
  if (tid < 64) maskv[0][tid] = mpre;
  __syncthreads();

  for (int kt = 0; kt < 32; kt++) {
    const int cur = kt & 1, nxt = cur ^ 1;

    // issue next tile's global loads first
    if (kt < 31) {
      const int k0n = (kt + 1) * 64;
      kpre0 = *(const int4*)&kb[(tokbase + k0n + sr) * DIM + h * 64 + sc * 8];
      vpre0 = *(const int4*)&vT[((size_t)bh * 64 + sr) * SEQ + k0n + sc * 8];
      kpre1 = *(const int4*)&kb[(tokbase + k0n + sr + 32) * DIM + h * 64 + sc * 8];
      vpre1 = *(const int4*)&vT[((size_t)bh * 64 + sr + 32) * SEQ + k0n + sc * 8];
      if (tid < 64) mpre = (1.0f - mask[tokbase + k0n + tid]) * (-10000.0f * LOG2E);
    }

    // S^T = K Q^T (base-2 domain): s2[kb][rb][r], key = kb*16 + hi*4 + r
    f32x4 s2[4][2];
#pragma unroll
    for (int kb4 = 0; kb4 < 4; kb4++)
#pragma unroll
      for (int rb = 0; rb < 2; rb++) { s2[kb4][rb][0] = 0.f; s2[kb4][rb][1] = 0.f; s2[kb4][rb][2] = 0.f; s2[kb4][rb][3] = 0.f; }
#pragma unroll
    for (int ks = 0; ks < 2; ks++) {
      short8 kf[4];
#pragma unroll
      for (int kb4 = 0; kb4 < 4; kb4++) {
        int row = kb4 * 16 + l15;
        kf[kb4] = *(const short8*)&Ks[cur][row * 64 + (((ks * 4 + hi) ^ (row & 7))) * 8];
      }
      __builtin_amdgcn_s_setprio(1);
#pragma unroll
      for (int kb4 = 0; kb4 < 4; kb4++)
#pragma unroll
        for (int rb = 0; rb < 2; rb++)
          s2[kb4][rb] = __builtin_amdgcn_mfma_f32_16x16x32_bf16(kf[kb4], qf[rb][ks], s2[kb4][rb], 0, 0, 0);
      __builtin_amdgcn_s_setprio(0);
    }

    // mask + scale (per-key, in-lane)
#pragma unroll
    for (int kb4 = 0; kb4 < 4; kb4++) {
      f32x4 mkv = *(const f32x4*)&maskv[cur][kb4 * 16 + hi * 4];
#pragma unroll
      for (int rb = 0; rb < 2; rb++)
#pragma unroll
        for (int r = 0; r < 4; r++)
          s2[kb4][rb][r] = s2[kb4][rb][r] * SCL2 + mkv[r];
    }

    // row-max: in-lane 16 + 2-step cross-hi shfl
    float tm[2];
#pragma unroll
    for (int rb = 0; rb < 2; rb++) {
      float t0m = fmaxf(fmaxf(s2[0][rb][0], s2[0][rb][1]), fmaxf(s2[0][rb][2], s2[0][rb][3]));
      float t1m = fmaxf(fmaxf(s2[1][rb][0], s2[1][rb][1]), fmaxf(s2[1][rb][2], s2[1][rb][3]));
      float t2m = fmaxf(fmaxf(s2[2][rb][0], s2[2][rb][1]), fmaxf(s2[2][rb][2], s2[2][rb][3]));
      float t3m = fmaxf(fmaxf(s2[3][rb][0], s2[3][rb][1]), fmaxf(s2[3][rb][2], s2[3][rb][3]));
      float t = fmaxf(fmaxf(t0m, t1m), fmaxf(t2m, t3m));
      t = fmaxf(t, __shfl_xor(t, 16));
      t = fmaxf(t, __shfl_xor(t, 32));
      tm[rb] = t;
    }

    // defer-max (T13)
    bool need = (tm[0] > mo[0] + THR2) || (tm[1] > mo[1] + THR2);
    if (__any(need)) {
      float al[2];
#pragma unroll
      for (int rb = 0; rb < 2; rb++) {
        float mn = fmaxf(mo[rb], tm[rb]);
        al[rb] = fast_exp2(mo[rb] - mn);
        mo[rb] = mn;
        ls[rb] *= al[rb];
      }
      // broadcast al for o-rows (row index = hi*4 + r, held by lane l15 = hi*4+r)
#pragma unroll
      for (int rb = 0; rb < 2; rb++)
#pragma unroll
        for (int r = 0; r < 4; r++) {
          float ab = __shfl(al[rb], hi * 4 + r);
#pragma unroll
          for (int db = 0; db < 4; db++) o[rb][db][r] *= ab;
        }
    }

    // exp + row-sum (in-lane 16 + 2-step shfl)
#pragma unroll
    for (int rb = 0; rb < 2; rb++) {
      float rsv = 0.f;
#pragma unroll
      for (int kb4 = 0; kb4 < 4; kb4++)
#pragma unroll
        for (int r = 0; r < 4; r++) {
          float pv = fast_exp2(s2[kb4][rb][r] - mo[rb]);
          s2[kb4][rb][r] = pv;
          rsv += pv;
        }
      rsv += __shfl_xor(rsv, 16);
      rsv += __shfl_xor(rsv, 32);
      ls[rb] += rsv;
    }

    // P -> LDS: 4 consecutive keys per write, 8x ds_write_b64 (wave-private rows)
#pragma unroll
    for (int rb = 0; rb < 2; rb++) {
      int rowb = (wv * 32 + rb * 16 + l15) * 72;
#pragma unroll
      for (int kb4 = 0; kb4 < 4; kb4++) {
        unsigned lo = pack2(s2[kb4][rb][0], s2[kb4][rb][1]);
        unsigned hi2 = pack2(s2[kb4][rb][2], s2[kb4][rb][3]);
        *(uint2*)&Ps[rowb + kb4 * 16 + hi * 4] = make_uint2(lo, hi2);
      }
    }

    // O += P V from buf[cur]
#pragma unroll
    for (int ks = 0; ks < 2; ks++) {
      short8 pf[2];
#pragma unroll
      for (int rb = 0; rb < 2; rb++) {
        int row = wv * 32 + rb * 16 + l15;
        pf[rb] = *(const short8*)&Ps[row * 72 + ks * 32 + hi * 8];
      }
      short8 vf[4];
#pragma unroll
      for (int db = 0; db < 4; db++) {
        int row = db * 16 + l15;
        vf[db] = *(const short8*)&Vs[cur][row * 64 + (((ks * 4 + hi) ^ (row & 7))) * 8];
      }
      __builtin_amdgcn_s_setprio(1);
#pragma unroll
      for (int rb = 0; rb < 2; rb++)
#pragma unroll
        for (int db = 0; db < 4; db++)
          o[rb][db] = __builtin_amdgcn_mfma_f32_16x16x32_bf16(pf[rb], vf[db], o[rb][db], 0, 0, 0);
      __builtin_amdgcn_s_setprio(0);
    }

    // write prefetched tile into buf[nxt]
    if (kt < 31) {
      *(int4*)&Ks[nxt][sr * 64 + sslot] = kpre0;
      *(int4*)&Vs[nxt][sr * 64 + sslot] = vpre0;
      *(int4*)&Ks[nxt][(sr + 32) * 64 + sslot2] = kpre1;
      *(int4*)&Vs[nxt][(sr + 32) * 64 + sslot2] = vpre1;
      if (tid < 64) maskv[nxt][tid] = mpre;
    }
    __syncthreads();   // ONE barrier per tile
  }

  // epilogue: write O (ls broadcast per row), fused amax
  float am = 0.f;
#pragma unroll
  for (int rb = 0; rb < 2; rb++)
#pragma unroll
    for (int r = 0; r < 4; r++) {
      float lsb = __shfl(ls[rb], hi * 4 + r);
      float inv = 1.0f / lsb;
      size_t row = tokbase + q0 + wv * 32 + rb * 16 + hi * 4 + r;
#pragma unroll
      for (int db = 0; db < 4; db++) {
        float val = o[rb][db][r] * inv;
        am = fmaxf(am, fabsf(val));
        obuf[row * DIM + h * 64 + db * 16 + l15] = val;
      }
    }
#pragma unroll
  for (int off = 32; off > 0; off >>= 1) am = fmaxf(am, __shfl_down(am, off));
  if (lane == 0) wmax[wv] = am;
  __syncthreads();
  if (tid == 0)
    atomicMax(amax_slot, __float_as_uint(fmaxf(fmaxf(wmax[0], wmax[1]), fmaxf(wmax[2], wmax[3]))));
}

// ---------------- launcher ----------------
extern "C" void kernel_launch(void* const* d_in, const int* in_sizes, int n_in,
                              void* d_out, int out_size, void* d_ws, size_t ws_size,
                              hipStream_t stream) {
  const float* x     = (const float*)d_in[0];
  const float* mask  = (const float*)d_in[1];
  const float* q_W   = (const float*)d_in[2];
  const float* q_b   = (const float*)d_in[3];
  const float* q_A   = (const float*)d_in[4];
  const float* q_B   = (const float*)d_in[5];
  const float* k_W   = (const float*)d_in[6];
  const float* k_b   = (const float*)d_in[7];
  const float* k_A   = (const float*)d_in[8];
  const float* k_B   = (const float*)d_in[9];
  const float* v_W   = (const float*)d_in[10];
  const float* v_b   = (const float*)d_in[11];
  const float* v_A   = (const float*)d_in[12];
  const float* v_B   = (const float*)d_in[13];
  const float* o_W   = (const float*)d_in[14];
  const float* o_b   = (const float*)d_in[15];
  const float* o_A   = (const float*)d_in[16];
  const float* o_B   = (const float*)d_in[17];
  float* out = (float*)d_out;

  char* ws = (char*)d_ws;
  const size_t MB = 1u << 20;
  unsigned* slots = (unsigned*)ws;                  // 6 amax slots
  float* t_q = (float*)(ws + 4096);
  float* t_k = t_q + MROWS * 8;
  float* t_v = t_k + MROWS * 8;
  float* t_o = t_v + MROWS * 8;
  ushort_t* xc  = (ushort_t*)(ws + 1 * MB);
  ushort_t* qWc = (ushort_t*)(ws + 9 * MB);
  ushort_t* kWc = (ushort_t*)(ws + 11 * MB);
  ushort_t* vWc = (ushort_t*)(ws + 13 * MB);
  ushort_t* oWc = (ushort_t*)(ws + 15 * MB);
  ushort_t* qbb = (ushort_t*)(ws + 17 * MB);
  ushort_t* kbb = (ushort_t*)(ws + 25 * MB);
  ushort_t* vbb = (ushort_t*)(ws + 33 * MB);
  ushort_t* vTb = (ushort_t*)(ws + 41 * MB);
  float*    abuf = (float*)(ws + 49 * MB);
  ushort_t* ac  = (ushort_t*)(ws + 65 * MB);

  (void)hipMemsetAsync(ws, 0, 64, stream);

  const int NX4 = (MROWS * DIM) / 4;
  const int NW4 = (DIM * DIM) / 4;

  amax5_kernel<<<dim3(256, 5), 256, 0, stream>>>(x, q_W, k_W, v_W, o_W, NX4, NW4, slots);
  quant4_kernel<<<dim3(128, 4), 256, 0, stream>>>(q_W, k_W, v_W, o_W,
                                                  qWc, kWc, vWc, oWc, NW4, slots);

  lora_quant_kernel<3><<<MROWS, 256, 0, stream>>>(x, slots + 0, xc, q_A, k_A, v_A,
                                                  t_q, t_k, t_v);

  ProjSet pq = { qWc, slots + 1, q_b, t_q, q_B, qbb };
  ProjSet pk = { kWc, slots + 2, k_b, t_k, k_B, kbb };
  ProjSet pv = { vWc, slots + 3, v_b, t_v, v_B, vbb };
  proj_qkv_kernel<<<dim3(DIM / 128, MROWS / 128, 3), 256, 0, stream>>>(xc, slots + 0, pq, pk, pv);

  vtrans_kernel<<<dim3(SEQ / 64, BSZ * NHEAD), 256, 0, stream>>>(vbb, vTb);

  attn7_kernel<<<512, 256, 0, stream>>>(qbb, kbb, vTb, mask, abuf, slots + 5);

  lora_quant_kernel<1><<<MROWS, 256, 0, stream>>>(abuf, slots + 5, ac, o_A, nullptr, nullptr,
                                                  t_o, nullptr, nullptr);

  proj_out_kernel<<<dim3(DIM / 64, MROWS / 128), 256, 0, stream>>>(
      ac, oWc, slots + 5, slots + 4, o_b, t_o, o_B, out);
}